// Round 1
// baseline (919.807 us; speedup 1.0000x reference)
//
#include <hip/hip_runtime.h>

#define BB 512
#define TT 2048
#define HD 13

// ---------- fast math helpers ----------
__device__ __forceinline__ float fexp2(float x){ return __builtin_amdgcn_exp2f(x); }
__device__ __forceinline__ float frcp(float x){ return __builtin_amdgcn_rcpf(x); }
// sigmoid(x) = 1/(1+2^(-x*log2e))
__device__ __forceinline__ float sigm(float x){ return frcp(1.f + fexp2(-1.4426950408889634f*x)); }
// tanh(x) = 1 - 2/(2^(2x*log2e)+1)
__device__ __forceinline__ float tanhfast(float x){ return 1.f - 2.f*frcp(1.f + fexp2(2.8853900817779268f*x)); }

__device__ __forceinline__ unsigned short f2bf(float f){
  unsigned u = __float_as_uint(f);
  u += 0x7fffu + ((u>>16)&1u);          // round-to-nearest-even
  return (unsigned short)(u>>16);
}
__device__ __forceinline__ float bflo(unsigned u){ return __uint_as_float(u<<16); }
__device__ __forceinline__ float bfhi(unsigned u){ return __uint_as_float(u & 0xffff0000u); }

// ---------- pass 1: xg[b][t][j][q] = bf16( x[b,t,:]·W_ih[q*13+j,:] + b_ih + b_hh ) ----------
__global__ __launch_bounds__(256) void k_xg(const float* __restrict__ x,
                                            const float* __restrict__ Wih,
                                            const float* __restrict__ bih,
                                            const float* __restrict__ bhh,
                                            uint2* __restrict__ xg)
{
  int tid = blockIdx.x*256 + threadIdx.x;        // exactly B*T*13 threads
  int bt  = tid / 13;
  int j   = tid - bt*13;
  const float* xr = x + (size_t)bt*13;
  float xv[13];
  #pragma unroll
  for (int k=0;k<13;k++) xv[k] = xr[k];
  float a[4];
  #pragma unroll
  for (int q=0;q<4;q++){
    int g = q*13 + j;
    float acc = bih[g] + bhh[g];
    #pragma unroll
    for (int k=0;k<13;k++) acc += Wih[g*13+k]*xv[k];
    a[q] = acc;
  }
  uint2 pk;
  pk.x = (unsigned)f2bf(a[0]) | ((unsigned)f2bf(a[1])<<16);
  pk.y = (unsigned)f2bf(a[2]) | ((unsigned)f2bf(a[3])<<16);
  xg[(size_t)bt*13 + j] = pk;
}

// ---------- pass 2: the recurrence. 4 chains/wave, lane=(c<<4)|j ----------
// lane j owns hidden unit j: computes all 4 gates (52 FMA), updates c,h locally;
// one cross-lane phase/step: 13 independent ds_swizzle broadcasts of h within the 16-group.
template<bool WS>
__global__ __launch_bounds__(64) void k_rec(
    const float* __restrict__ x,   const float* __restrict__ Whh,
    const float* __restrict__ Wih, const float* __restrict__ bih, const float* __restrict__ bhh,
    const float* __restrict__ fcw, const float* __restrict__ fcb,
    const uint2* __restrict__ xg,  float* __restrict__ hs, float* __restrict__ out)
{
  const int lane = threadIdx.x;
  const int c    = lane >> 4;
  const int j    = lane & 15;
  const int b    = blockIdx.x*4 + c;
  const bool act = (j < 13);
  const int jj   = act ? j : 0;

  float whh[4][13];
  #pragma unroll
  for (int q=0;q<4;q++){
    #pragma unroll
    for (int k=0;k<13;k++){
      float w = Whh[(q*13+jj)*13 + k];
      whh[q][k] = act ? w : 0.f;
    }
  }

  float wih[4][13]; float bias[4]; float fcwj = 0.f;
  const float fcb0 = fcb[0];
  if (!WS){
    #pragma unroll
    for (int q=0;q<4;q++){
      #pragma unroll
      for (int k=0;k<13;k++){
        float w = Wih[(q*13+jj)*13 + k];
        wih[q][k] = act ? w : 0.f;
      }
      bias[q] = bih[q*13+jj] + bhh[q*13+jj];
    }
    fcwj = act ? fcw[jj] : 0.f;
  }

  const uint2* xp = xg + (size_t)b*(TT*13) + j;   // WS path
  const float* xpf = x + (size_t)b*(TT*13) + jj;  // fallback path
  float*       hp  = hs ? (hs + (size_t)b*(TT*13) + j) : nullptr;
  float*       op  = out + (size_t)b*TT;

  float h = 0.f, cs = 0.f;
  uint2 xv = {0,0}; float xsc = 0.f;
  if (WS) xv = *xp; else xsc = *xpf;

  for (int t=0; t<TT; ++t){
    // prefetch next step's input projection (WS overread lands inside ws -> safe)
    uint2 xvn = {0,0}; float xscn = 0.f;
    if (WS) { xp += 13; xvn = *xp; }
    else    { if (t+1 < TT) xpf += 13; xscn = *xpf; }

    // broadcast h_k (k=0..12) from lane k of each 16-group to all lanes of the group
    float hb[13];
    {
      int hbits = __float_as_int(h);
      #define HB(k) hb[k] = __int_as_float(__builtin_amdgcn_ds_swizzle(hbits, ((k)<<5)|0x10));
      HB(0) HB(1) HB(2) HB(3) HB(4) HB(5) HB(6) HB(7) HB(8) HB(9) HB(10) HB(11) HB(12)
      #undef HB
    }

    float a0,a1,a2,a3;
    if (WS){
      a0 = bflo(xv.x); a1 = bfhi(xv.x); a2 = bflo(xv.y); a3 = bfhi(xv.y);
    } else {
      float xb[13];
      int xbits = __float_as_int(xsc);
      #define XB(k) xb[k] = __int_as_float(__builtin_amdgcn_ds_swizzle(xbits, ((k)<<5)|0x10));
      XB(0) XB(1) XB(2) XB(3) XB(4) XB(5) XB(6) XB(7) XB(8) XB(9) XB(10) XB(11) XB(12)
      #undef XB
      a0 = bias[0]; a1 = bias[1]; a2 = bias[2]; a3 = bias[3];
      #pragma unroll
      for (int k=0;k<13;k++){
        float xk = xb[k];
        a0 += wih[0][k]*xk; a1 += wih[1][k]*xk; a2 += wih[2][k]*xk; a3 += wih[3][k]*xk;
      }
    }

    #pragma unroll
    for (int k=0;k<13;k++){
      float hk = hb[k];
      a0 += whh[0][k]*hk; a1 += whh[1][k]*hk; a2 += whh[2][k]*hk; a3 += whh[3][k]*hk;
    }

    float ig = sigm(a0), fg = sigm(a1), gg = tanhfast(a2), og = sigm(a3);
    cs = fg*cs + ig*gg;
    h  = og * tanhfast(cs);

    if (WS){
      if (act) *hp = h;
      hp += 13;
      xv = xvn;
    } else {
      float p = act ? fcwj*h : 0.f;
      #define RED(m) p += __int_as_float(__builtin_amdgcn_ds_swizzle(__float_as_int(p), ((m)<<10)|0x1F));
      RED(1) RED(2) RED(4) RED(8)
      #undef RED
      if (j == 0) op[t] = sigm(p + fcb0);
      xsc = xscn;
    }
  }
}

// ---------- pass 3: out[bt] = sigmoid( fc_w · h[bt,:] + fc_b ) ----------
__global__ __launch_bounds__(256) void k_out(const float* __restrict__ hs,
                                             const float* __restrict__ fcw,
                                             const float* __restrict__ fcb,
                                             float* __restrict__ out)
{
  __shared__ float tile[256*13];
  size_t base = (size_t)blockIdx.x * 256;
  const float* src = hs + base*13;
  #pragma unroll
  for (int i=0;i<13;i++) tile[threadIdx.x + i*256] = src[threadIdx.x + i*256];
  __syncthreads();
  float acc = fcb[0];
  #pragma unroll
  for (int k=0;k<13;k++) acc += fcw[k]*tile[threadIdx.x*13 + k];
  out[base + threadIdx.x] = sigm(acc);
}

extern "C" void kernel_launch(void* const* d_in, const int* in_sizes, int n_in,
                              void* d_out, int out_size, void* d_ws, size_t ws_size,
                              hipStream_t stream)
{
  const float* x   = (const float*)d_in[0];
  const float* Wih = (const float*)d_in[1];
  const float* Whh = (const float*)d_in[2];
  const float* bih = (const float*)d_in[3];
  const float* bhh = (const float*)d_in[4];
  const float* fcw = (const float*)d_in[5];
  const float* fcb = (const float*)d_in[6];
  float* out = (float*)d_out;

  const size_t XG_BYTES = (size_t)BB*TT*52*2;   // 109,051,904  (bf16 [B,T,13,4])
  const size_t HS_BYTES = (size_t)BB*TT*13*4;   //  54,525,952  (f32  [B,T,13])

  if (ws_size >= XG_BYTES + HS_BYTES){
    uint2* xg = (uint2*)d_ws;
    float* hs = (float*)((char*)d_ws + XG_BYTES);
    k_xg<<<dim3((BB*TT*13)/256), dim3(256), 0, stream>>>(x, Wih, bih, bhh, xg);
    k_rec<true><<<dim3(BB/4), dim3(64), 0, stream>>>(x, Whh, Wih, bih, bhh, fcw, fcb, xg, hs, out);
    k_out<<<dim3((BB*TT)/256), dim3(256), 0, stream>>>(hs, fcw, fcb, out);
  } else {
    k_rec<false><<<dim3(BB/4), dim3(64), 0, stream>>>(x, Whh, Wih, bih, bhh, fcw, fcb, nullptr, nullptr, out);
  }
}

// Round 2
// 396.800 us; speedup vs baseline: 2.3181x; 2.3181x over previous
//
#include <hip/hip_runtime.h>

#define BB 512
#define TT 2048
#define HD 13

// ---------- fast math helpers ----------
__device__ __forceinline__ float fexp2(float x){ return __builtin_amdgcn_exp2f(x); }
__device__ __forceinline__ float frcp(float x){ return __builtin_amdgcn_rcpf(x); }
__device__ __forceinline__ float sigm(float x){ return frcp(1.f + fexp2(-1.4426950408889634f*x)); }
__device__ __forceinline__ float tanhfast(float x){ return 1.f - 2.f*frcp(1.f + fexp2(2.8853900817779268f*x)); }

__device__ __forceinline__ unsigned short f2bf(float f){
  unsigned u = __float_as_uint(f);
  u += 0x7fffu + ((u>>16)&1u);          // round-to-nearest-even
  return (unsigned short)(u>>16);
}
__device__ __forceinline__ float bfu_lo(unsigned b){ return __uint_as_float(b<<16); }
__device__ __forceinline__ float bfu_hi(unsigned b){ return __uint_as_float(b & 0xffff0000u); }

// quad broadcast: every lane of a quad gets lane (quad_base + r)'s value
#define QB(v, ctrl) __int_as_float(__builtin_amdgcn_mov_dpp(__float_as_int(v), (ctrl), 0xF, 0xF, true))

// ---------- pass 1: xg[b][tg][e][u] = bf16 preact, e = q*13+j, u = t&7 ----------
// block: 256 threads covering (b, t0..t0+255); LDS-staged, coalesced in and out.
__global__ __launch_bounds__(256) void k_xg2(const float* __restrict__ x,
                                             const float* __restrict__ Wih,
                                             const float* __restrict__ bih,
                                             const float* __restrict__ bhh,
                                             unsigned* __restrict__ xg_u)
{
  __shared__ float    xs[13*256];      // x rows for 256 timesteps
  __shared__ unsigned ot[32*212];      // 32 t-groups x 424 ushorts (416 + pad)
  const int tid = threadIdx.x;
  const int b   = blockIdx.x >> 3;
  const int t0  = (blockIdx.x & 7) << 8;

  const float* xsrc = x + ((size_t)b*TT + t0)*13;
  #pragma unroll
  for (int it=0; it<13; ++it) xs[tid + it*256] = xsrc[tid + it*256];
  __syncthreads();

  float xv[13];
  #pragma unroll
  for (int k=0;k<13;k++) xv[k] = xs[tid*13+k];

  const int tgl = tid >> 3, u = tid & 7;
  unsigned short* otp = (unsigned short*)ot;
  #pragma unroll 2
  for (int g=0; g<52; ++g){            // g = q*13+j, uniform -> scalar W loads
    float acc = bih[g] + bhh[g];
    #pragma unroll
    for (int k=0;k<13;k++) acc = fmaf(Wih[g*13+k], xv[k], acc);
    otp[tgl*424 + g*8 + u] = f2bf(acc);
  }
  __syncthreads();

  unsigned* dst = xg_u + ((((size_t)b*256 + (t0>>3))*416) >> 1);
  #pragma unroll
  for (int it=0; it<26; ++it){         // 6656 uints, coalesced
    int i2  = tid + it*256;
    int us  = i2*2;
    int t2  = (int)((unsigned)us / 416u);
    int rem = us - t2*416;
    dst[i2] = ot[t2*212 + (rem>>1)];
  }
}

// ---------- pass 2: recurrence. 1 chain per wave; lane 4j+q owns gate q of unit j ----------
__device__ __forceinline__ void lstm_step(float xv, const float* __restrict__ w,
                                          float kq, float gm, float ga,
                                          float& h, float& c, float* hb,
                                          bool wr, float*& hpp)
{
  // gate preact: 13 FMAs with SGPR h operands, split into 2 chains
  float a0 = fmaf(w[0], hb[0], xv);
  a0 = fmaf(w[1], hb[1], a0);
  a0 = fmaf(w[2], hb[2], a0);
  a0 = fmaf(w[3], hb[3], a0);
  a0 = fmaf(w[4], hb[4], a0);
  a0 = fmaf(w[5], hb[5], a0);
  a0 = fmaf(w[6], hb[6], a0);
  float a1 = w[7]*hb[7];
  a1 = fmaf(w[8],  hb[8],  a1);
  a1 = fmaf(w[9],  hb[9],  a1);
  a1 = fmaf(w[10], hb[10], a1);
  a1 = fmaf(w[11], hb[11], a1);
  a1 = fmaf(w[12], hb[12], a1);
  float pre = a0 + a1;

  // uniform nonlinearity: y = 1/(1+2^(-kq*pre)); gate = gm*y + ga
  float y = frcp(1.f + fexp2(-kq*pre));
  float g = fmaf(gm, y, ga);

  // gather i,f,g,o within the quad via DPP
  float gi = QB(g, 0x00);
  float gf = QB(g, 0x55);
  float gg = QB(g, 0xAA);
  float go = QB(g, 0xFF);

  c = fmaf(gf, c, gi*gg);
  float tc = fmaf(2.f, frcp(1.f + fexp2(-2.8853900817779268f*c)), -1.f);
  h = go * tc;

  if (wr) *hpp = h;
  hpp += 13;

  // broadcast new h to SGPRs for next step
  #pragma unroll
  for (int k=0;k<13;k++)
    hb[k] = __int_as_float(__builtin_amdgcn_readlane(__float_as_int(h), 4*k));
}

__global__ __launch_bounds__(64) void k_rec2(const float* __restrict__ Whh,
                                             const unsigned short* __restrict__ xg,
                                             float* __restrict__ hs)
{
  const int lane = threadIdx.x;
  const int b    = blockIdx.x;
  const int q    = lane & 3;
  const int j    = lane >> 2;             // 0..15 (13..15 inactive padding)
  const int jc   = (j < 13) ? j : 12;
  const int e    = q*13 + jc;             // gate-major row index, < 52

  float w[13];
  #pragma unroll
  for (int k=0;k<13;k++) w[k] = Whh[e*13 + k];

  const float kq = (q==2) ? 2.8853900817779268f : 1.4426950408889634f;
  const float gm = (q==2) ? 2.f : 1.f;
  const float ga = (q==2) ? -1.f : 0.f;

  const char* gbase = (const char*)xg + ((size_t)b*256*416 + (size_t)e*8)*2;
  uint4 A  = *(const uint4*)(gbase);
  uint4 Bv = *(const uint4*)(gbase + 832);
  uint4 C  = *(const uint4*)(gbase + 2*832);

  float h = 0.f, c = 0.f;
  float hb[13];
  #pragma unroll
  for (int k=0;k<13;k++) hb[k] = 0.f;

  const bool wr = (q==0) && (j<13);
  float* hpp = hs + (size_t)b*TT*13 + j;

  for (int tg=0; tg<256; ++tg){
    const int pf = (tg+3 < 256) ? tg+3 : 255;
    uint4 nb = *(const uint4*)(gbase + (size_t)pf*832);

    lstm_step(bfu_lo(A.x), w, kq, gm, ga, h, c, hb, wr, hpp);
    lstm_step(bfu_hi(A.x), w, kq, gm, ga, h, c, hb, wr, hpp);
    lstm_step(bfu_lo(A.y), w, kq, gm, ga, h, c, hb, wr, hpp);
    lstm_step(bfu_hi(A.y), w, kq, gm, ga, h, c, hb, wr, hpp);
    lstm_step(bfu_lo(A.z), w, kq, gm, ga, h, c, hb, wr, hpp);
    lstm_step(bfu_hi(A.z), w, kq, gm, ga, h, c, hb, wr, hpp);
    lstm_step(bfu_lo(A.w), w, kq, gm, ga, h, c, hb, wr, hpp);
    lstm_step(bfu_hi(A.w), w, kq, gm, ga, h, c, hb, wr, hpp);

    A = Bv; Bv = C; C = nb;
  }
}

// ---------- pass 3: out[bt] = sigmoid( fc_w · h[bt,:] + fc_b ) ----------
__global__ __launch_bounds__(256) void k_out(const float* __restrict__ hs,
                                             const float* __restrict__ fcw,
                                             const float* __restrict__ fcb,
                                             float* __restrict__ out)
{
  __shared__ float tile[256*13];
  size_t base = (size_t)blockIdx.x * 256;
  const float* src = hs + base*13;
  #pragma unroll
  for (int i=0;i<13;i++) tile[threadIdx.x + i*256] = src[threadIdx.x + i*256];
  __syncthreads();
  float acc = fcb[0];
  #pragma unroll
  for (int k=0;k<13;k++) acc += fcw[k]*tile[threadIdx.x*13 + k];
  out[base + threadIdx.x] = sigm(acc);
}

// ---------- fallback (no workspace): Round-1 swizzle kernel, inline x-proj + FC ----------
__global__ __launch_bounds__(64) void k_rec_fb(
    const float* __restrict__ x,   const float* __restrict__ Whh,
    const float* __restrict__ Wih, const float* __restrict__ bih, const float* __restrict__ bhh,
    const float* __restrict__ fcw, const float* __restrict__ fcb,
    float* __restrict__ out)
{
  const int lane = threadIdx.x;
  const int c    = lane >> 4;
  const int j    = lane & 15;
  const int b    = blockIdx.x*4 + c;
  const bool act = (j < 13);
  const int jj   = act ? j : 0;

  float whh[4][13], wih[4][13], bias[4];
  #pragma unroll
  for (int q=0;q<4;q++){
    #pragma unroll
    for (int k=0;k<13;k++){
      float w1 = Whh[(q*13+jj)*13 + k];
      float w2 = Wih[(q*13+jj)*13 + k];
      whh[q][k] = act ? w1 : 0.f;
      wih[q][k] = act ? w2 : 0.f;
    }
    bias[q] = bih[q*13+jj] + bhh[q*13+jj];
  }
  const float fcwj = act ? fcw[jj] : 0.f;
  const float fcb0 = fcb[0];

  const float* xpf = x + (size_t)b*(TT*13) + jj;
  float* op = out + (size_t)b*TT;

  float h = 0.f, cs = 0.f;
  float xsc = *xpf;

  for (int t=0; t<TT; ++t){
    float xscn = 0.f;
    if (t+1 < TT) { xpf += 13; xscn = *xpf; }

    float hb[13], xb[13];
    {
      int hbits = __float_as_int(h);
      int xbits = __float_as_int(xsc);
      #define HB(k) hb[k] = __int_as_float(__builtin_amdgcn_ds_swizzle(hbits, ((k)<<5)|0x10)); \
                    xb[k] = __int_as_float(__builtin_amdgcn_ds_swizzle(xbits, ((k)<<5)|0x10));
      HB(0) HB(1) HB(2) HB(3) HB(4) HB(5) HB(6) HB(7) HB(8) HB(9) HB(10) HB(11) HB(12)
      #undef HB
    }
    float a0 = bias[0], a1 = bias[1], a2 = bias[2], a3 = bias[3];
    #pragma unroll
    for (int k=0;k<13;k++){
      float xk = xb[k], hk = hb[k];
      a0 += wih[0][k]*xk + whh[0][k]*hk;
      a1 += wih[1][k]*xk + whh[1][k]*hk;
      a2 += wih[2][k]*xk + whh[2][k]*hk;
      a3 += wih[3][k]*xk + whh[3][k]*hk;
    }
    float ig = sigm(a0), fg = sigm(a1), gg = tanhfast(a2), og = sigm(a3);
    cs = fg*cs + ig*gg;
    h  = og * tanhfast(cs);

    float p = act ? fcwj*h : 0.f;
    #define RED(m) p += __int_as_float(__builtin_amdgcn_ds_swizzle(__float_as_int(p), ((m)<<10)|0x1F));
    RED(1) RED(2) RED(4) RED(8)
    #undef RED
    if (j == 0) op[t] = sigm(p + fcb0);
    xsc = xscn;
  }
}

extern "C" void kernel_launch(void* const* d_in, const int* in_sizes, int n_in,
                              void* d_out, int out_size, void* d_ws, size_t ws_size,
                              hipStream_t stream)
{
  const float* x   = (const float*)d_in[0];
  const float* Wih = (const float*)d_in[1];
  const float* Whh = (const float*)d_in[2];
  const float* bih = (const float*)d_in[3];
  const float* bhh = (const float*)d_in[4];
  const float* fcw = (const float*)d_in[5];
  const float* fcb = (const float*)d_in[6];
  float* out = (float*)d_out;

  const size_t XG_BYTES = (size_t)BB*256*416*2;  // 109,051,904  bf16 [b][tg][52][8]
  const size_t HS_BYTES = (size_t)BB*TT*13*4;    //  54,525,952  f32  [b][t][13]

  if (ws_size >= XG_BYTES + HS_BYTES){
    unsigned* xg = (unsigned*)d_ws;
    float*    hs = (float*)((char*)d_ws + XG_BYTES);
    k_xg2<<<dim3(BB*8), dim3(256), 0, stream>>>(x, Wih, bih, bhh, xg);
    k_rec2<<<dim3(BB), dim3(64), 0, stream>>>(Whh, (const unsigned short*)xg, hs);
    k_out<<<dim3((BB*TT)/256), dim3(256), 0, stream>>>(hs, fcw, fcb, out);
  } else {
    k_rec_fb<<<dim3(BB/4), dim3(64), 0, stream>>>(x, Whh, Wih, bih, bhh, fcw, fcb, out);
  }
}